// Round 10
// baseline (1597.157 us; speedup 1.0000x reference)
//
#include <hip/hip_runtime.h>
#include <math.h>

#define BS   256
#define NN   255
#define DIM  128
#define GAMMA 0.07
#define NUM_ITERS 1000

typedef float v2f __attribute__((ext_vector_type(2)));

__device__ __forceinline__ double wred_d(double v) {
  #pragma unroll
  for (int k = 1; k < 64; k <<= 1) v += __shfl_xor(v, k, 64);
  return v;
}
__device__ __forceinline__ int wred_i(int v) {
  #pragma unroll
  for (int k = 1; k < 64; k <<= 1) v += __shfl_xor(v, k, 64);
  return v;
}

// lane-uniform float readlane
__device__ __forceinline__ float RLF(float v, int lane) {
  return __int_as_float(__builtin_amdgcn_readlane(__float_as_int(v), lane));
}

// DPP wave64 sum -> total broadcast via readlane(63). VALU-only.
template <int CTRL, int RMASK>
__device__ __forceinline__ float dpp_add(float x) {
  int t = __builtin_amdgcn_update_dpp(0, __float_as_int(x), CTRL, RMASK, 0xf, true);
  return x + __int_as_float(t);
}
__device__ __forceinline__ float wred64_dpp(float x) {
  x = dpp_add<0x111, 0xf>(x);   // row_shr:1
  x = dpp_add<0x112, 0xf>(x);   // row_shr:2
  x = dpp_add<0x114, 0xf>(x);   // row_shr:4
  x = dpp_add<0x118, 0xf>(x);   // row_shr:8
  x = dpp_add<0x142, 0xa>(x);   // row_bcast:15
  x = dpp_add<0x143, 0xc>(x);   // row_bcast:31; lane63 = total
  return RLF(x, 63);
}

// packed dual-fp32 FMA (VOP3P)
__device__ __forceinline__ void pk_fma(v2f& acc, const v2f& k, const v2f& y) {
  asm("v_pk_fma_f32 %0, %1, %2, %0" : "+v"(acc) : "v"(k), "v"(y));
}

// ---------------- kernel 1: normalized features, stored transposed fp64 ----------------
__global__ void k_ftr(const float* __restrict__ z, double* __restrict__ ftrT) {
  int b = blockIdx.x;
  int d = threadIdx.x;
  double z0 = (double)z[b * 256 + d];
  double z1 = (double)z[b * 256 + 128 + d];
  double n = sqrt(z0 * z0 + z1 * z1);
  n = fmax(n, 1e-12);
  ftrT[d * 512 + b]       = z0 / n;
  ftrT[d * 512 + 256 + b] = z1 / n;
}

// ---------------- kernel 2: K = exp(-gamma * dist), fp64 math, fp32 store ----------------
__global__ void k_K(const double* __restrict__ ftrT, float* __restrict__ K,
                    double* __restrict__ pk_knt, double* __restrict__ pos_arr) {
  int i = blockIdx.x;
  int t = threadIdx.x;
  __shared__ double rowi[DIM];
  __shared__ double redd[4];
  if (t < DIM) rowi[t] = ftrT[t * 512 + i];
  __syncthreads();
  double xn = 0.0;
  #pragma unroll 8
  for (int d = 0; d < DIM; ++d) xn += rowi[d] * rowi[d];

  double knt_part = 0.0;
  #pragma unroll
  for (int h = 0; h < 2; ++h) {
    int j = t + h * 256;
    double dot = 0.0, sq = 0.0;
    #pragma unroll 8
    for (int d = 0; d < DIM; ++d) {
      double f = ftrT[d * 512 + j];
      dot += rowi[d] * f;
      sq  += f * f;
    }
    double dist = xn + sq - 2.0 * dot;
    double kv = exp(-GAMMA * dist);
    K[i * 512 + j] = (float)kv;
    if (h == 1) {
      if (j == 256 + i) pos_arr[i] = kv;
      else knt_part += kv;
    }
  }
  double w = wred_d(knt_part);
  if ((t & 63) == 0) redd[t >> 6] = w;
  __syncthreads();
  if (t == 0) pk_knt[i] = redd[0] + redd[1] + redd[2] + redd[3];
}

// ---------------- kernel 3: per-batch PGD, ONE barrier per iteration ----------------
// 16 waves. Wave rg=(rb=rg&3, cb=rg>>2): rows [64rb,64rb+64) x col 64cb+l,
// K band in 32 reg pairs, matvec = 16 broadcast b128 + 32 v_pk_fma_f32.
// Solver state REPLICATED in all 16 waves (bit-identical, R8-verified).
// Each wave keeps a PRIVATE ytil copy in LDS (write+read same-wave -> no
// barrier, just lgkmcnt). part[] is double-buffered so region2 readers of
// buf never race region1 writers of buf^1. Net: single __syncthreads per
// iter, no serial single-wave phase (R9: ~1600 cyc/iter of barrier+wave0
// serial latency at VALUBusy 31%).
__global__ __launch_bounds__(1024, 4) void k_pgd(
    const float* __restrict__ K, const float* __restrict__ alpha_init,
    double* __restrict__ neg_arr, double* __restrict__ sa_arr,
    int* __restrict__ cnt1, int* __restrict__ cntp, int* __restrict__ cnt0) {
  int r = blockIdx.x;
  int tid = threadIdx.x;
  int l = tid & 63;
  int rg = tid >> 6;        // 0..15
  int rb = rg & 3;          // row band
  int cb = rg >> 2;         // col quarter
  int col = 64 * cb + l;    // this thread's matvec column

  __shared__ __align__(16) float ytw[16][BS];     // per-wave private y copies, 16 KB
  __shared__ __align__(16) float part[2][4][BS];  // double-buffered partials, 8 KB

  // stage K column band as row pairs
  v2f kp[32];
  #pragma unroll
  for (int j = 0; j < 32; ++j) {
    kp[j].x = K[(64 * rb + 2 * j + 0) * 512 + col];
    kp[j].y = K[(64 * rb + 2 * j + 1) * 512 + col];
  }
  #pragma unroll
  for (int j = 0; j < 32; ++j)
    asm volatile("" : "+v"(kp[j]));   // block rematerialization

  // replicated a-indexed state: lane l holds a = 4l..4l+3 (dummy 0 at a==r)
  float al[4], ap[4], yv[4], kv[4], rm2[4];
  #pragma unroll
  for (int k = 0; k < 4; ++k) {
    int a = 4 * l + k;
    if (a == r) {
      al[k] = 0.f; ap[k] = 0.f; yv[k] = 0.f; kv[k] = 0.f; rm2[k] = 0.f;
    } else {
      int c = a - (a > r ? 1 : 0);
      float v = alpha_init[r * NN + c];
      v = fminf(fmaxf(v, 0.f), 1.f);
      al[k] = v; ap[k] = v; yv[k] = v;
      kv[k] = 1.0f - K[r * 512 + a];
      rm2[k] = 2.0f;
    }
  }
  float S = wred64_dpp((yv[0] + yv[1]) + (yv[2] + yv[3]));
  {
    float4 y4 = {yv[0], yv[1], yv[2], yv[3]};
    *(float4*)&ytw[rg][4 * l] = y4;   // own-wave copy; no barrier needed
  }

  for (int it = 0; it < NUM_ITERS; ++it) {
    int b = it & 1;
    // ---- region 1: matvec partial (rows 64rb..64rb+64, column col) ----
    const float4* yb = (const float4*)&ytw[rg][64 * rb];
    v2f acc = {0.f, 0.f};
    #pragma unroll
    for (int jq = 0; jq < 16; ++jq) {
      float4 yq = yb[jq];                      // wave-broadcast b128 (own slot)
      v2f ylo = {yq.x, yq.y};
      v2f yhi = {yq.z, yq.w};
      pk_fma(acc, kp[2 * jq + 0], ylo);
      pk_fma(acc, kp[2 * jq + 1], yhi);
    }
    part[b][rb][col] = acc.x + acc.y;          // conflict-free b32
    __syncthreads();                           // B1: all partials of buf b visible

    // ---- region 2: replicated update (identical in all 16 waves) ----
    float4 p0 = *(const float4*)&part[b][0][4 * l];
    float4 p1 = *(const float4*)&part[b][1][4 * l];
    float4 p2 = *(const float4*)&part[b][2][4 * l];
    float4 p3 = *(const float4*)&part[b][3][4 * l];
    float gr = (part[b][0][r] + part[b][1][r]) + (part[b][2][r] + part[b][3][r]);
    float gA[4];
    gA[0] = (p0.x + p1.x) + (p2.x + p3.x);
    gA[1] = (p0.y + p1.y) + (p2.y + p3.y);
    gA[2] = (p0.z + p1.z) + (p2.z + p3.z);
    gA[3] = (p0.w + p1.w) + (p2.w + p3.w);
    // a==r col: kv=rm2=yv=0 and gA==gr (same add tree) -> g = 0 exactly
    float g[4];
    #pragma unroll
    for (int k = 0; k < 4; ++k)
      g[k] = (gA[k] - gr) - rm2[k] + kv[k] * S + 0.1f * yv[k];
    float n2 = wred64_dpp((g[0] * g[0] + g[1] * g[1]) + (g[2] * g[2] + g[3] * g[3]));
    float sinv = 0.001f / (sqrtf(n2) + 1e-12f);
    float beta = (float)(it + 1) / ((float)(it + 1) + 3.0f);
    float ysum = 0.f;
    #pragma unroll
    for (int k = 0; k < 4; ++k) {
      float na = fminf(fmaxf(fmaf(-sinv, g[k], yv[k]), 0.f), 1.f);
      ap[k] = al[k];
      al[k] = na;
      yv[k] = fmaf(beta, na - ap[k], na);
      ysum += yv[k];
    }
    S = wred64_dpp(ysum);
    float4 y4 = {yv[0], yv[1], yv[2], yv[3]};
    *(float4*)&ytw[rg][4 * l] = y4;            // own-wave copy; next region1 reads it
    // no second barrier: part[b^1] writes can't race part[b] readers
  }

  // epilogue: all waves hold identical final state; wave 0 reduces+writes
  if (rg == 0) {
    double nl = 0.0, sa = 0.0;
    int c1 = 0, cp = 0, cz = 0;
    #pragma unroll
    for (int k = 0; k < 4; ++k) {
      int a = 4 * l + k;
      if (a != r) {
        float kx = K[a * 512 + 256 + r];     // KnT[r, c(a)]
        nl += (double)al[k] * (double)kx;
        sa += (double)al[k];
        c1 += (al[k] == 1.0f);
        cp += (al[k] > 0.0f);
        cz += (al[k] == 0.0f);
      }
    }
    nl = wred_d(nl); sa = wred_d(sa);
    c1 = wred_i(c1); cp = wred_i(cp); cz = wred_i(cz);
    if (l == 0) {
      neg_arr[r] = nl;
      sa_arr[r]  = sa;
      cnt1[r] = c1; cntp[r] = cp; cnt0[r] = cz;
    }
  }
}

// ---------------- kernel 4: final reduction to the 6 scalar outputs ----------------
__global__ void k_fin(const double* __restrict__ pk_knt, const double* __restrict__ pos_arr,
                      const double* __restrict__ neg_arr, const double* __restrict__ sa_arr,
                      const int* __restrict__ cnt1, const int* __restrict__ cntp,
                      const int* __restrict__ cnt0, float* __restrict__ out) {
  int t = threadIdx.x;  // 256
  __shared__ double rd[16];
  __shared__ int ri[12];
  double knt = pk_knt[t];
  double pos = pos_arr[t];
  double neg = neg_arr[t];
  double pl  = sa_arr[t] * pos_arr[t];
  int a1 = cnt1[t], ap = cntp[t], a0 = cnt0[t];
  knt = wred_d(knt); pos = wred_d(pos); neg = wred_d(neg); pl = wred_d(pl);
  a1 = wred_i(a1); ap = wred_i(ap); a0 = wred_i(a0);
  int w = t >> 6;
  if ((t & 63) == 0) {
    rd[w] = knt; rd[4 + w] = pos; rd[8 + w] = neg; rd[12 + w] = pl;
    ri[w] = a1; ri[4 + w] = ap; ri[8 + w] = a0;
  }
  __syncthreads();
  if (t == 0) {
    double kntS = rd[0] + rd[1] + rd[2] + rd[3];
    double posS = rd[4] + rd[5] + rd[6] + rd[7];
    double negS = rd[8] + rd[9] + rd[10] + rd[11];
    double plS  = rd[12] + rd[13] + rd[14] + rd[15];
    int c1t = ri[0] + ri[1] + ri[2] + ri[3];
    int cpt = ri[4] + ri[5] + ri[6] + ri[7];
    int c0t = ri[8] + ri[9] + ri[10] + ri[11];
    out[0] = (float)(negS / 256.0 - plS / 256.0);
    out[1] = (float)(posS / 256.0);
    out[2] = (float)(kntS / (256.0 * 255.0));
    out[3] = (float)c1t / ((float)cpt + 1e-10f);
    out[4] = (float)c0t / 65280.0f;
    out[5] = 0.0f;
  }
}

extern "C" void kernel_launch(void* const* d_in, const int* in_sizes, int n_in,
                              void* d_out, int out_size, void* d_ws, size_t ws_size,
                              hipStream_t stream) {
  const float* z     = (const float*)d_in[0];
  const float* ainit = (const float*)d_in[1];
  char* ws = (char*)d_ws;
  double* ftrT   = (double*)ws;                       // 512 KB
  float*  K      = (float*)(ws + 524288);             // 512 KB
  double* pk_knt = (double*)(ws + 1048576);
  double* pos_a  = (double*)(ws + 1048576 + 2048);
  double* neg_a  = (double*)(ws + 1048576 + 4096);
  double* sa_a   = (double*)(ws + 1048576 + 6144);
  int* cnt1 = (int*)(ws + 1048576 + 8192);
  int* cntp = (int*)(ws + 1048576 + 8192 + 1024);
  int* cnt0 = (int*)(ws + 1048576 + 8192 + 2048);
  float* out = (float*)d_out;

  k_ftr<<<256, 128, 0, stream>>>(z, ftrT);
  k_K  <<<256, 256, 0, stream>>>(ftrT, K, pk_knt, pos_a);
  k_pgd<<<256, 1024, 0, stream>>>(K, ainit, neg_a, sa_a, cnt1, cntp, cnt0);
  k_fin<<<1, 256, 0, stream>>>(pk_knt, pos_a, neg_a, sa_a, cnt1, cntp, cnt0, out);
}

// Round 11
// 927.095 us; speedup vs baseline: 1.7228x; 1.7228x over previous
//
#include <hip/hip_runtime.h>
#include <math.h>

#define BS   256
#define NN   255
#define DIM  128
#define GAMMA 0.07
#define NUM_ITERS 1000

typedef float v2f __attribute__((ext_vector_type(2)));

__device__ __forceinline__ double wred_d(double v) {
  #pragma unroll
  for (int k = 1; k < 64; k <<= 1) v += __shfl_xor(v, k, 64);
  return v;
}
__device__ __forceinline__ int wred_i(int v) {
  #pragma unroll
  for (int k = 1; k < 64; k <<= 1) v += __shfl_xor(v, k, 64);
  return v;
}

// lane-uniform float readlane
__device__ __forceinline__ float RLF(float v, int lane) {
  return __int_as_float(__builtin_amdgcn_readlane(__float_as_int(v), lane));
}

// DPP wave64 sum -> total broadcast via readlane(63). VALU-only.
template <int CTRL, int RMASK>
__device__ __forceinline__ float dpp_add(float x) {
  int t = __builtin_amdgcn_update_dpp(0, __float_as_int(x), CTRL, RMASK, 0xf, true);
  return x + __int_as_float(t);
}
__device__ __forceinline__ float wred64_dpp(float x) {
  x = dpp_add<0x111, 0xf>(x);   // row_shr:1
  x = dpp_add<0x112, 0xf>(x);   // row_shr:2
  x = dpp_add<0x114, 0xf>(x);   // row_shr:4
  x = dpp_add<0x118, 0xf>(x);   // row_shr:8
  x = dpp_add<0x142, 0xa>(x);   // row_bcast:15
  x = dpp_add<0x143, 0xc>(x);   // row_bcast:31; lane63 = total
  return RLF(x, 63);
}

// packed dual-fp32 FMA (VOP3P)
__device__ __forceinline__ void pk_fma(v2f& acc, const v2f& k, const v2f& y) {
  asm("v_pk_fma_f32 %0, %1, %2, %0" : "+v"(acc) : "v"(k), "v"(y));
}

// fast reciprocal-sqrt: v_rsq_f32 + one Newton step (~0.5 ulp)
__device__ __forceinline__ float rsq_nr(float x) {
  float r;
  asm("v_rsq_f32 %0, %1" : "=v"(r) : "v"(x));
  r = r * (1.5f - 0.5f * x * r * r);
  return r;
}

// ---------------- kernel 1: normalized features, stored transposed fp64 ----------------
__global__ void k_ftr(const float* __restrict__ z, double* __restrict__ ftrT) {
  int b = blockIdx.x;
  int d = threadIdx.x;
  double z0 = (double)z[b * 256 + d];
  double z1 = (double)z[b * 256 + 128 + d];
  double n = sqrt(z0 * z0 + z1 * z1);
  n = fmax(n, 1e-12);
  ftrT[d * 512 + b]       = z0 / n;
  ftrT[d * 512 + 256 + b] = z1 / n;
}

// ---------------- kernel 2: K = exp(-gamma * dist), fp64 math, fp32 store ----------------
__global__ void k_K(const double* __restrict__ ftrT, float* __restrict__ K,
                    double* __restrict__ pk_knt, double* __restrict__ pos_arr) {
  int i = blockIdx.x;
  int t = threadIdx.x;
  __shared__ double rowi[DIM];
  __shared__ double redd[4];
  if (t < DIM) rowi[t] = ftrT[t * 512 + i];
  __syncthreads();
  double xn = 0.0;
  #pragma unroll 8
  for (int d = 0; d < DIM; ++d) xn += rowi[d] * rowi[d];

  double knt_part = 0.0;
  #pragma unroll
  for (int h = 0; h < 2; ++h) {
    int j = t + h * 256;
    double dot = 0.0, sq = 0.0;
    #pragma unroll 8
    for (int d = 0; d < DIM; ++d) {
      double f = ftrT[d * 512 + j];
      dot += rowi[d] * f;
      sq  += f * f;
    }
    double dist = xn + sq - 2.0 * dot;
    double kv = exp(-GAMMA * dist);
    K[i * 512 + j] = (float)kv;
    if (h == 1) {
      if (j == 256 + i) pos_arr[i] = kv;
      else knt_part += kv;
    }
  }
  double w = wred_d(knt_part);
  if ((t & 63) == 0) redd[t >> 6] = w;
  __syncthreads();
  if (t == 0) pk_knt[i] = redd[0] + redd[1] + redd[2] + redd[3];
}

// ---------------- kernel 3: per-batch PGD (R9 skeleton, shortened serial chain) ----------------
// 16 waves; wave rg=(rb=rg&3, cb=rg>>2): rows [64rb,64rb+64) x col 64cb+l.
// Region2 on wave0 only (2 barriers). Serial-path trims vs R9:
//  - S computed by wave 1 during region1 phase (DPP), passed via S_lds
//  - beta from a precomputed 1024-entry LDS table (kills IEEE div in chain)
//  - sinv via v_rsq+Newton (kills sqrt+div sequence)
//  - gr partials delivered as grs[4] (one b128 read, no dynamic addressing)
__global__ __launch_bounds__(1024, 4) void k_pgd(
    const float* __restrict__ K, const float* __restrict__ alpha_init,
    double* __restrict__ neg_arr, double* __restrict__ sa_arr,
    int* __restrict__ cnt1, int* __restrict__ cntp, int* __restrict__ cnt0) {
  int r = blockIdx.x;
  int tid = threadIdx.x;
  int l = tid & 63;
  int rg = tid >> 6;        // 0..15
  int rb = rg & 3;          // row band
  int cb = rg >> 2;         // col quarter
  int col = 64 * cb + l;    // this thread's matvec column

  __shared__ __align__(16) float ytil[BS];      // a-indexed, ytil[r]==0 always
  __shared__ __align__(16) float part[4][BS];   // [row band][a-col]
  __shared__ __align__(16) float grs[4];        // per-band partial of column r
  __shared__ float S_lds[1];
  __shared__ float betat[1024];

  // beta table: betat[i] = i/(i+3) fp32 (read at index it+1)
  betat[tid] = (float)tid / ((float)tid + 3.0f);

  // stage K column band as row pairs
  v2f kp[32];
  #pragma unroll
  for (int j = 0; j < 32; ++j) {
    kp[j].x = K[(64 * rb + 2 * j + 0) * 512 + col];
    kp[j].y = K[(64 * rb + 2 * j + 1) * 512 + col];
  }
  #pragma unroll
  for (int j = 0; j < 32; ++j)
    asm volatile("" : "+v"(kp[j]));   // block rematerialization

  // wave-0-only solver state: lane l holds a = 4l..4l+3 (dummy 0 at a==r)
  float al[4], ap[4], yv[4], kv[4], rm2[4];
  if (rg == 0) {
    #pragma unroll
    for (int k = 0; k < 4; ++k) {
      int a = 4 * l + k;
      if (a == r) {
        al[k] = 0.f; ap[k] = 0.f; yv[k] = 0.f; kv[k] = 0.f; rm2[k] = 0.f;
      } else {
        int c = a - (a > r ? 1 : 0);
        float v = alpha_init[r * NN + c];
        v = fminf(fmaxf(v, 0.f), 1.f);
        al[k] = v; ap[k] = v; yv[k] = v;
        kv[k] = 1.0f - K[r * 512 + a];
        rm2[k] = 2.0f;
      }
    }
    float4 y4 = {yv[0], yv[1], yv[2], yv[3]};
    *(float4*)&ytil[4 * l] = y4;     // a-indexed store (slot r holds 0)
  }
  __syncthreads();                   // state + betat visible

  for (int it = 0; it < NUM_ITERS; ++it) {
    // ---- phase A (region1, all waves); wave1 also produces S off-path ----
    if (rg == 1) {
      float4 yq = *(const float4*)&ytil[4 * l];
      float Sv = wred64_dpp((yq.x + yq.y) + (yq.z + yq.w));
      if (l == 0) S_lds[0] = Sv;
    }
    const float4* yb = (const float4*)&ytil[64 * rb];
    v2f acc = {0.f, 0.f};
    #pragma unroll
    for (int jq = 0; jq < 16; ++jq) {
      float4 yq = yb[jq];                      // wave-broadcast b128
      v2f ylo = {yq.x, yq.y};
      v2f yhi = {yq.z, yq.w};
      pk_fma(acc, kp[2 * jq + 0], ylo);
      pk_fma(acc, kp[2 * jq + 1], yhi);
    }
    float pv = acc.x + acc.y;
    part[rb][col] = pv;                        // conflict-free b32
    if (col == r) grs[rb] = pv;                // column-r partial, fixed slot
    __syncthreads();                           // B1: partials + S visible

    // ---- phase B: region2 on wave 0 only ----
    if (rg == 0) {
      float4 p0 = *(const float4*)&part[0][4 * l];
      float4 p1 = *(const float4*)&part[1][4 * l];
      float4 p2 = *(const float4*)&part[2][4 * l];
      float4 p3 = *(const float4*)&part[3][4 * l];
      float4 g4 = *(const float4*)&grs[0];
      float Sv = S_lds[0];
      float beta = betat[it + 1];
      float gr = (g4.x + g4.y) + (g4.z + g4.w);
      float gA[4];
      gA[0] = (p0.x + p1.x) + (p2.x + p3.x);
      gA[1] = (p0.y + p1.y) + (p2.y + p3.y);
      gA[2] = (p0.z + p1.z) + (p2.z + p3.z);
      gA[3] = (p0.w + p1.w) + (p2.w + p3.w);
      // a==r col: kv=rm2=yv=0 and gA==gr (same add tree) -> g = 0 exactly
      float g[4];
      #pragma unroll
      for (int k = 0; k < 4; ++k)
        g[k] = (gA[k] - gr) - rm2[k] + kv[k] * Sv + 0.1f * yv[k];
      float n2 = wred64_dpp((g[0] * g[0] + g[1] * g[1]) + (g[2] * g[2] + g[3] * g[3]));
      float sinv = 0.001f * rsq_nr(n2);        // ~0.5ulp vs 0.001/(sqrt+1e-12)
      #pragma unroll
      for (int k = 0; k < 4; ++k) {
        float na = fminf(fmaxf(fmaf(-sinv, g[k], yv[k]), 0.f), 1.f);
        ap[k] = al[k];
        al[k] = na;
        yv[k] = fmaf(beta, na - ap[k], na);
      }
      float4 y4 = {yv[0], yv[1], yv[2], yv[3]};
      *(float4*)&ytil[4 * l] = y4;             // one b128, conflict-free
    }
    __syncthreads();                           // B2: ytil ready
  }

  // epilogue: wave 0 holds the state — single-wave fp64 reductions
  if (rg == 0) {
    double nl = 0.0, sa = 0.0;
    int c1 = 0, cp = 0, cz = 0;
    #pragma unroll
    for (int k = 0; k < 4; ++k) {
      int a = 4 * l + k;
      if (a != r) {
        float kx = K[a * 512 + 256 + r];     // KnT[r, c(a)]
        nl += (double)al[k] * (double)kx;
        sa += (double)al[k];
        c1 += (al[k] == 1.0f);
        cp += (al[k] > 0.0f);
        cz += (al[k] == 0.0f);
      }
    }
    nl = wred_d(nl); sa = wred_d(sa);
    c1 = wred_i(c1); cp = wred_i(cp); cz = wred_i(cz);
    if (l == 0) {
      neg_arr[r] = nl;
      sa_arr[r]  = sa;
      cnt1[r] = c1; cntp[r] = cp; cnt0[r] = cz;
    }
  }
}

// ---------------- kernel 4: final reduction to the 6 scalar outputs ----------------
__global__ void k_fin(const double* __restrict__ pk_knt, const double* __restrict__ pos_arr,
                      const double* __restrict__ neg_arr, const double* __restrict__ sa_arr,
                      const int* __restrict__ cnt1, const int* __restrict__ cntp,
                      const int* __restrict__ cnt0, float* __restrict__ out) {
  int t = threadIdx.x;  // 256
  __shared__ double rd[16];
  __shared__ int ri[12];
  double knt = pk_knt[t];
  double pos = pos_arr[t];
  double neg = neg_arr[t];
  double pl  = sa_arr[t] * pos_arr[t];
  int a1 = cnt1[t], ap = cntp[t], a0 = cnt0[t];
  knt = wred_d(knt); pos = wred_d(pos); neg = wred_d(neg); pl = wred_d(pl);
  a1 = wred_i(a1); ap = wred_i(ap); a0 = wred_i(a0);
  int w = t >> 6;
  if ((t & 63) == 0) {
    rd[w] = knt; rd[4 + w] = pos; rd[8 + w] = neg; rd[12 + w] = pl;
    ri[w] = a1; ri[4 + w] = ap; ri[8 + w] = a0;
  }
  __syncthreads();
  if (t == 0) {
    double kntS = rd[0] + rd[1] + rd[2] + rd[3];
    double posS = rd[4] + rd[5] + rd[6] + rd[7];
    double negS = rd[8] + rd[9] + rd[10] + rd[11];
    double plS  = rd[12] + rd[13] + rd[14] + rd[15];
    int c1t = ri[0] + ri[1] + ri[2] + ri[3];
    int cpt = ri[4] + ri[5] + ri[6] + ri[7];
    int c0t = ri[8] + ri[9] + ri[10] + ri[11];
    out[0] = (float)(negS / 256.0 - plS / 256.0);
    out[1] = (float)(posS / 256.0);
    out[2] = (float)(kntS / (256.0 * 255.0));
    out[3] = (float)c1t / ((float)cpt + 1e-10f);
    out[4] = (float)c0t / 65280.0f;
    out[5] = 0.0f;
  }
}

extern "C" void kernel_launch(void* const* d_in, const int* in_sizes, int n_in,
                              void* d_out, int out_size, void* d_ws, size_t ws_size,
                              hipStream_t stream) {
  const float* z     = (const float*)d_in[0];
  const float* ainit = (const float*)d_in[1];
  char* ws = (char*)d_ws;
  double* ftrT   = (double*)ws;                       // 512 KB
  float*  K      = (float*)(ws + 524288);             // 512 KB
  double* pk_knt = (double*)(ws + 1048576);
  double* pos_a  = (double*)(ws + 1048576 + 2048);
  double* neg_a  = (double*)(ws + 1048576 + 4096);
  double* sa_a   = (double*)(ws + 1048576 + 6144);
  int* cnt1 = (int*)(ws + 1048576 + 8192);
  int* cntp = (int*)(ws + 1048576 + 8192 + 1024);
  int* cnt0 = (int*)(ws + 1048576 + 8192 + 2048);
  float* out = (float*)d_out;

  k_ftr<<<256, 128, 0, stream>>>(z, ftrT);
  k_K  <<<256, 256, 0, stream>>>(ftrT, K, pk_knt, pos_a);
  k_pgd<<<256, 1024, 0, stream>>>(K, ainit, neg_a, sa_a, cnt1, cntp, cnt0);
  k_fin<<<1, 256, 0, stream>>>(pk_knt, pos_a, neg_a, sa_a, cnt1, cntp, cnt0, out);
}